// Round 1
// baseline (871.142 us; speedup 1.0000x reference)
//
#include <hip/hip_runtime.h>

constexpr int B = 16, C = 256, O = 256, H = 128, W = 128, K = 3;
constexpr int GROUPS = 32;
constexpr int CPG = C / GROUPS;   // 8 input channels per group
constexpr int OPG = O / GROUPS;   // 8 output channels per group
constexpr int HW = H * W;         // 16384
constexpr float EPS = 1e-7f;

constexpr int TILE = 32;
constexpr int HALO = TILE + 2;    // 34
constexpr int XSTR = 36;          // padded LDS row stride (36 % 4 == 0 -> float4 aligned; 36 mod 32 = 4 -> conflict-free)
constexpr int PLANE = HALO * XSTR; // 1224 floats (1224*4 B is 16B-multiple)
constexpr int NW = CPG * K * K * OPG; // 576 combined weights per (b,g)

// ---------------- Kernel 1: per-(b,c) mean and 1/(std+eps) ----------------
__global__ __launch_bounds__(256) void stats_kernel(const float* __restrict__ x,
                                                    float2* __restrict__ stats) {
    int bc = blockIdx.x;                       // 0..B*C-1
    const float4* xv = (const float4*)(x + (size_t)bc * HW);
    int tid = threadIdx.x;
    float sum = 0.f, sumsq = 0.f;
#pragma unroll
    for (int it = 0; it < HW / 4 / 256; ++it) {  // 16 iters
        float4 v = xv[tid + it * 256];
        sum   += v.x + v.y + v.z + v.w;
        sumsq += v.x*v.x + v.y*v.y + v.z*v.z + v.w*v.w;
    }
#pragma unroll
    for (int off = 32; off > 0; off >>= 1) {
        sum   += __shfl_down(sum, off);
        sumsq += __shfl_down(sumsq, off);
    }
    __shared__ float s_sum[4], s_sq[4];
    int wave = tid >> 6;
    if ((tid & 63) == 0) { s_sum[wave] = sum; s_sq[wave] = sumsq; }
    __syncthreads();
    if (tid == 0) {
        float ts = s_sum[0] + s_sum[1] + s_sum[2] + s_sum[3];
        float tq = s_sq[0] + s_sq[1] + s_sq[2] + s_sq[3];
        float mean = ts / (float)HW;
        float var  = (tq - ts * ts / (float)HW) / (float)(HW - 1); // ddof=1
        var = fmaxf(var, 0.f);
        float stdv = sqrtf(var) + EPS;                             // eps on std, like torch
        stats[bc] = make_float2(mean, 1.0f / stdv);
    }
}

// ---------------- Kernel 2: fold 1x1 grouped conv into 3x3 weights ----------------
// CW[b][g][i][ky][kx][o'] = sum_j pw[b, g*OPG+o', j] * dw[b, g*OPG+j, i, ky, kx]
__global__ __launch_bounds__(256) void combine_kernel(const float* __restrict__ dw,
                                                      const float* __restrict__ pw,
                                                      float* __restrict__ cw) {
    int idx = blockIdx.x * 256 + threadIdx.x;   // exactly B*GROUPS*NW threads
    int o  = idx % OPG;  int t = idx / OPG;
    int kx = t % K;      t /= K;
    int ky = t % K;      t /= K;
    int i  = t % CPG;    t /= CPG;
    int g  = t % GROUPS; int b = t / GROUPS;
    const float* pwp = pw + (size_t)(b * O + g * OPG + o) * CPG;
    float acc = 0.f;
#pragma unroll
    for (int j = 0; j < CPG; ++j) {
        float wd = dw[(((size_t)(b * O + g * OPG + j) * CPG + i) * K + ky) * K + kx];
        acc = fmaf(pwp[j], wd, acc);
    }
    cw[idx] = acc;
}

// ---------------- Kernel 3: fused norm + grouped 3x3 conv + bias ----------------
__global__ __launch_bounds__(256) void conv_kernel(const float* __restrict__ x,
                                                   const float* __restrict__ cw,
                                                   const float* __restrict__ bias,
                                                   const float2* __restrict__ stats,
                                                   float* __restrict__ out) {
    __shared__ float  sx[CPG * PLANE];   // 9792 floats = 39168 B
    __shared__ float  sw[NW];            // 576 floats
    __shared__ float2 sstat[CPG];

    int blk  = blockIdx.x;
    int tile = blk & 15;          // 16 tiles per (b,g)
    int g    = (blk >> 4) & 31;
    int b    = blk >> 9;
    int x0g  = (tile & 3) * TILE;
    int y0g  = (tile >> 2) * TILE;
    int tid  = threadIdx.x;

    // stage combined weights + stats
    const float* cwp = cw + (size_t)(b * GROUPS + g) * NW;
#pragma unroll
    for (int e = tid; e < NW; e += 256) sw[e] = cwp[e];
    if (tid < CPG) sstat[tid] = stats[b * C + g * CPG + tid];
    __syncthreads();

    // stage 8 normalized, zero-padded input planes (34x34)
    const float* xbase = x + (size_t)(b * C + g * CPG) * HW;
    for (int e = tid; e < CPG * HALO * HALO; e += 256) {
        int i = e / (HALO * HALO);
        int r = (e / HALO) % HALO;
        int c = e % HALO;
        int gy = y0g + r - 1, gx = x0g + c - 1;
        float v = 0.f;
        if (gy >= 0 && gy < H && gx >= 0 && gx < W) {
            float2 ms = sstat[i];
            v = (xbase[(size_t)i * HW + gy * W + gx] - ms.x) * ms.y;
        }
        sx[i * PLANE + r * XSTR + c] = v;
    }
    __syncthreads();

    // each thread: 4 contiguous pixels in x, all 8 output channels
    int xl = (tid & 7) * 4;      // local pixel x of first of 4
    int py = tid >> 3;           // local pixel y (0..31)

    float acc[OPG][4];
#pragma unroll
    for (int o = 0; o < OPG; ++o)
#pragma unroll
        for (int p = 0; p < 4; ++p) acc[o][p] = 0.f;

#pragma unroll 1
    for (int i = 0; i < CPG; ++i) {
#pragma unroll
        for (int ky = 0; ky < K; ++ky) {
            const float* rp = &sx[i * PLANE + (py + ky) * XSTR + xl];
            float4 a  = *(const float4*)rp;        // 16B aligned
            float2 b2 = *(const float2*)(rp + 4);
            float xv[6] = {a.x, a.y, a.z, a.w, b2.x, b2.y};
#pragma unroll
            for (int kx = 0; kx < K; ++kx) {
                const float* wp = &sw[((i * K + ky) * K + kx) * OPG];
                float4 w0 = *(const float4*)wp;
                float4 w1 = *(const float4*)(wp + 4);
                float wv[8] = {w0.x, w0.y, w0.z, w0.w, w1.x, w1.y, w1.z, w1.w};
#pragma unroll
                for (int o = 0; o < OPG; ++o)
#pragma unroll
                    for (int p = 0; p < 4; ++p)
                        acc[o][p] = fmaf(wv[o], xv[kx + p], acc[o][p]);
            }
        }
    }

    // epilogue: add bias, store float4 per output channel
    const float* bp = bias + b * O + g * OPG;
    int gy = y0g + py, gxs = x0g + xl;
    float* op = out + (((size_t)(b * O + g * OPG) * H + gy) * W + gxs);
#pragma unroll
    for (int o = 0; o < OPG; ++o) {
        float bv = bp[o];
        float4 r = make_float4(acc[o][0] + bv, acc[o][1] + bv,
                               acc[o][2] + bv, acc[o][3] + bv);
        *(float4*)(op + (size_t)o * HW) = r;
    }
}

extern "C" void kernel_launch(void* const* d_in, const int* in_sizes, int n_in,
                              void* d_out, int out_size, void* d_ws, size_t ws_size,
                              hipStream_t stream) {
    const float* x    = (const float*)d_in[0];
    const float* dw   = (const float*)d_in[1];
    const float* pw   = (const float*)d_in[2];
    const float* bias = (const float*)d_in[3];
    float* out = (float*)d_out;

    // workspace layout: stats (B*C float2 = 32 KB), then combined weights (1.18 MB)
    float2* stats = (float2*)d_ws;
    float*  cwbuf = (float*)((char*)d_ws + B * C * sizeof(float2));

    stats_kernel<<<B * C, 256, 0, stream>>>(x, stats);
    combine_kernel<<<(B * GROUPS * NW) / 256, 256, 0, stream>>>(dw, pw, cwbuf);
    conv_kernel<<<B * GROUPS * 16, 256, 0, stream>>>(x, cwbuf, bias, stats, out);
}